// Round 1
// baseline (612.091 us; speedup 1.0000x reference)
//
#include <hip/hip_runtime.h>

#define N_NODES 50000
#define N_EDGES 800000

// ---------------- small utility kernels ----------------

__global__ void zero_f32_k(float* __restrict__ p, int n) {
    int i = blockIdx.x * blockDim.x + threadIdx.x;
    if (i < n) p[i] = 0.f;
}

__global__ void deg_count_k(const int* __restrict__ dst, float* __restrict__ deg, int nE) {
    int i = blockIdx.x * blockDim.x + threadIdx.x;
    if (i < nE) atomicAdd(deg + dst[i], 1.0f);
}

__global__ void inv_deg_k(const float* __restrict__ deg, float* __restrict__ inv, int n) {
    int i = blockIdx.x * blockDim.x + threadIdx.x;
    if (i < n) inv[i] = 1.0f / fmaxf(deg[i], 1.0f);
}

// single-block exclusive scan of deg -> rowptr, also initializes cursor
__global__ __launch_bounds__(1024) void scan_k(const float* __restrict__ deg,
                                               int* __restrict__ rowptr,
                                               int* __restrict__ cursor, int n) {
    __shared__ int sums[1024];
    int tid = threadIdx.x;
    int per = (n + 1023) >> 10;   // 49
    int base = tid * per;
    int s = 0;
    for (int i = 0; i < per; ++i) {
        int idx = base + i;
        if (idx < n) s += (int)deg[idx];
    }
    sums[tid] = s;
    __syncthreads();
    for (int off = 1; off < 1024; off <<= 1) {
        int v = (tid >= off) ? sums[tid - off] : 0;
        __syncthreads();
        sums[tid] += v;
        __syncthreads();
    }
    int run = (tid == 0) ? 0 : sums[tid - 1];
    for (int i = 0; i < per; ++i) {
        int idx = base + i;
        if (idx < n) {
            rowptr[idx] = run;
            cursor[idx] = run;
            run += (int)deg[idx];
        }
    }
    if (tid == 1023) rowptr[n] = sums[1023];
}

__global__ void scatter_k(const int* __restrict__ src, const int* __restrict__ dst,
                          int* __restrict__ cursor, int* __restrict__ csr, int nE) {
    int i = blockIdx.x * blockDim.x + threadIdx.x;
    if (i < nE) {
        int pos = atomicAdd(cursor + dst[i], 1);
        csr[pos] = src[i];
    }
}

// ---------------- fp32 GEMM: out[N,DOUT] = A[N,128] @ W[128,DOUT] (+bias) ----------------
// tile: 64 rows x 64 cols per block, 256 threads, 4x4 acc per thread.

template <int DOUT>
__global__ __launch_bounds__(256) void gemm_k(const float* __restrict__ A,
                                              const float* __restrict__ W,
                                              const float* __restrict__ bias,
                                              float* __restrict__ out, int N) {
    __shared__ float As[128][65];   // [k][m], stride 65 words: conflict-light
    __shared__ float Ws[128][64];   // [k][n]
    const int bm = blockIdx.x * 64;
    const int bn = blockIdx.y * 64;
    const int tid = threadIdx.x;

    {
        // A tile: coalesced float4 loads, transpose into LDS
        const int kq = tid & 31, rl = tid >> 5;   // kq: which float4 of the row, rl: row subgroup
#pragma unroll
        for (int i = 0; i < 8; ++i) {
            int r = rl + i * 8;
            int row = bm + r;
            float4 v = make_float4(0.f, 0.f, 0.f, 0.f);
            if (row < N) v = *(const float4*)(A + (size_t)row * 128 + kq * 4);
            As[kq * 4 + 0][r] = v.x;
            As[kq * 4 + 1][r] = v.y;
            As[kq * 4 + 2][r] = v.z;
            As[kq * 4 + 3][r] = v.w;
        }
        // W tile: 128 x 64 slice starting at column bn
        const int cq = tid & 15, kl = tid >> 4;
#pragma unroll
        for (int i = 0; i < 8; ++i) {
            int k = kl + i * 16;
            *(float4*)(&Ws[k][cq * 4]) = *(const float4*)(W + (size_t)k * DOUT + bn + cq * 4);
        }
    }
    __syncthreads();

    const int tc = tid & 15, tr = tid >> 4;
    float acc[4][4] = {};
#pragma unroll 8
    for (int k = 0; k < 128; ++k) {
        float a0 = As[k][tr * 4 + 0];
        float a1 = As[k][tr * 4 + 1];
        float a2 = As[k][tr * 4 + 2];
        float a3 = As[k][tr * 4 + 3];
        float4 b = *(const float4*)(&Ws[k][tc * 4]);
        acc[0][0] += a0 * b.x; acc[0][1] += a0 * b.y; acc[0][2] += a0 * b.z; acc[0][3] += a0 * b.w;
        acc[1][0] += a1 * b.x; acc[1][1] += a1 * b.y; acc[1][2] += a1 * b.z; acc[1][3] += a1 * b.w;
        acc[2][0] += a2 * b.x; acc[2][1] += a2 * b.y; acc[2][2] += a2 * b.z; acc[2][3] += a2 * b.w;
        acc[3][0] += a3 * b.x; acc[3][1] += a3 * b.y; acc[3][2] += a3 * b.z; acc[3][3] += a3 * b.w;
    }

    float4 bb = make_float4(0.f, 0.f, 0.f, 0.f);
    if (bias) bb = *(const float4*)(bias + bn + tc * 4);
#pragma unroll
    for (int i = 0; i < 4; ++i) {
        int row = bm + tr * 4 + i;
        if (row < N) {
            float4 o;
            o.x = acc[i][0] + bb.x;
            o.y = acc[i][1] + bb.y;
            o.z = acc[i][2] + bb.z;
            o.w = acc[i][3] + bb.w;
            *(float4*)(out + (size_t)row * DOUT + bn + tc * 4) = o;
        }
    }
}

// ---------------- aggregation: out[v] += inv[v] * sum_{j} z[csr[j]]  (+optional relu) ----------------
// one wave (64 lanes) per node; lane-parallel over feature columns.

template <int DOUT, bool RELU>
__global__ __launch_bounds__(256) void agg_k(const float* __restrict__ z,
                                             const int* __restrict__ rowptr,
                                             const int* __restrict__ csr,
                                             const float* __restrict__ inv,
                                             float* __restrict__ out, int N) {
    int gwave = (blockIdx.x * 256 + threadIdx.x) >> 6;
    int lane = threadIdx.x & 63;
    if (gwave >= N) return;
    const int v = gwave;
    int start = rowptr[v], end = rowptr[v + 1];

    if constexpr (DOUT == 128) {
        const float2* zp = (const float2*)z;
        float2 a0 = {0.f, 0.f}, a1 = {0.f, 0.f};
        int j = start;
        for (; j + 1 < end; j += 2) {
            int u0 = csr[j], u1 = csr[j + 1];
            float2 v0 = zp[(size_t)u0 * 64 + lane];
            float2 v1 = zp[(size_t)u1 * 64 + lane];
            a0.x += v0.x; a0.y += v0.y;
            a1.x += v1.x; a1.y += v1.y;
        }
        if (j < end) {
            int u = csr[j];
            float2 vv = zp[(size_t)u * 64 + lane];
            a0.x += vv.x; a0.y += vv.y;
        }
        float s = inv[v];
        float2* op = (float2*)(out + (size_t)v * 128) + lane;
        float2 o = *op;
        o.x += (a0.x + a1.x) * s;
        o.y += (a0.y + a1.y) * s;
        if (RELU) { o.x = fmaxf(o.x, 0.f); o.y = fmaxf(o.y, 0.f); }
        *op = o;
    } else {
        float a0 = 0.f, a1 = 0.f;
        int j = start;
        for (; j + 1 < end; j += 2) {
            int u0 = csr[j], u1 = csr[j + 1];
            a0 += z[(size_t)u0 * DOUT + lane];
            a1 += z[(size_t)u1 * DOUT + lane];
        }
        if (j < end) a0 += z[(size_t)csr[j] * DOUT + lane];
        float s = inv[v];
        float* op = out + (size_t)v * DOUT + lane;
        float o = *op + (a0 + a1) * s;
        if (RELU) o = fmaxf(o, 0.f);
        *op = o;
    }
}

// ---------------- launch ----------------

extern "C" void kernel_launch(void* const* d_in, const int* in_sizes, int n_in,
                              void* d_out, int out_size, void* d_ws, size_t ws_size,
                              hipStream_t stream) {
    const float* x       = (const float*)d_in[0];
    const int*   src     = (const int*)d_in[1];
    const int*   dst     = (const int*)d_in[2];
    const float* Wself0  = (const float*)d_in[3];
    const float* Wneigh0 = (const float*)d_in[4];
    const float* b0      = (const float*)d_in[5];
    const float* Wself1  = (const float*)d_in[6];
    const float* Wneigh1 = (const float*)d_in[7];
    const float* b1      = (const float*)d_in[8];
    const float* Wself2  = (const float*)d_in[9];
    const float* Wneigh2 = (const float*)d_in[10];
    const float* b2      = (const float*)d_in[11];
    float* out = (float*)d_out;

    char* ws = (char*)d_ws;
    size_t off = 0;
    auto alloc = [&](size_t bytes) -> void* {
        void* p = ws + off;
        off += (bytes + 255) & ~(size_t)255;
        return p;
    };
    float* deg    = (float*)alloc((size_t)N_NODES * 4);
    float* inv    = (float*)alloc((size_t)N_NODES * 4);
    int*   rowptr = (int*)alloc((size_t)(N_NODES + 1) * 4);
    int*   cursor = (int*)alloc((size_t)N_NODES * 4);
    int*   csr    = (int*)alloc((size_t)N_EDGES * 4);
    float* bufA   = (float*)alloc((size_t)N_NODES * 128 * 4);
    float* bufB   = (float*)alloc((size_t)N_NODES * 128 * 4);
    float* bufZ   = (float*)alloc((size_t)N_NODES * 128 * 4);

    dim3 b256(256);
    const int nodeBlocks = (N_NODES + 255) / 256;
    const int edgeBlocks = (N_EDGES + 255) / 256;
    const int gemmRows   = (N_NODES + 63) / 64;   // 782
    const int aggBlocks  = (N_NODES + 3) / 4;     // 4 waves (nodes) per 256-thread block

    // graph structure (per call; deterministic up to fp-commutative reordering)
    zero_f32_k<<<nodeBlocks, b256, 0, stream>>>(deg, N_NODES);
    deg_count_k<<<edgeBlocks, b256, 0, stream>>>(dst, deg, N_EDGES);
    inv_deg_k<<<nodeBlocks, b256, 0, stream>>>(deg, inv, N_NODES);
    scan_k<<<1, 1024, 0, stream>>>(deg, rowptr, cursor, N_NODES);
    scatter_k<<<edgeBlocks, b256, 0, stream>>>(src, dst, cursor, csr, N_EDGES);

    // layer 0: x[50000,128] -> bufA
    gemm_k<128><<<dim3(gemmRows, 2), b256, 0, stream>>>(x, Wneigh0, nullptr, bufZ, N_NODES);
    gemm_k<128><<<dim3(gemmRows, 2), b256, 0, stream>>>(x, Wself0, b0, bufA, N_NODES);
    agg_k<128, true><<<aggBlocks, b256, 0, stream>>>(bufZ, rowptr, csr, inv, bufA, N_NODES);

    // layer 1: bufA -> bufB
    gemm_k<128><<<dim3(gemmRows, 2), b256, 0, stream>>>(bufA, Wneigh1, nullptr, bufZ, N_NODES);
    gemm_k<128><<<dim3(gemmRows, 2), b256, 0, stream>>>(bufA, Wself1, b1, bufB, N_NODES);
    agg_k<128, true><<<aggBlocks, b256, 0, stream>>>(bufZ, rowptr, csr, inv, bufB, N_NODES);

    // layer 2: bufB -> out[50000,64]
    gemm_k<64><<<dim3(gemmRows, 1), b256, 0, stream>>>(bufB, Wneigh2, nullptr, bufZ, N_NODES);
    gemm_k<64><<<dim3(gemmRows, 1), b256, 0, stream>>>(bufB, Wself2, b2, out, N_NODES);
    agg_k<64, false><<<aggBlocks, b256, 0, stream>>>(bufZ, rowptr, csr, inv, out, N_NODES);
}

// Round 2
// 482.724 us; speedup vs baseline: 1.2680x; 1.2680x over previous
//
#include <hip/hip_runtime.h>

#define N_NODES 50000
#define N_EDGES 800000
#define NB_SCAN 196   // ceil(50000 / 256)

// ---------------- CSR build ----------------

__global__ void deg_count_k(const int* __restrict__ dst, int* __restrict__ deg, int nE) {
    int i = blockIdx.x * blockDim.x + threadIdx.x;
    if (i < nE) atomicAdd(deg + dst[i], 1);
}

// per-256-chunk sums (coalesced), LDS tree reduce
__global__ __launch_bounds__(256) void block_sum_k(const int* __restrict__ deg,
                                                   int* __restrict__ bsum, int n) {
    __shared__ int s[256];
    int t = threadIdx.x, b = blockIdx.x;
    int i = b * 256 + t;
    s[t] = (i < n) ? deg[i] : 0;
    __syncthreads();
#pragma unroll
    for (int off = 128; off > 0; off >>= 1) {
        if (t < off) s[t] += s[t + off];
        __syncthreads();
    }
    if (t == 0) bsum[b] = s[0];
}

// single small block: exclusive scan of the <=256 block sums
__global__ __launch_bounds__(256) void scan_bsum_k(const int* __restrict__ bsum,
                                                   int* __restrict__ boff,
                                                   int* __restrict__ rowptr_last, int nb) {
    __shared__ int s[256];
    int t = threadIdx.x;
    int v = (t < nb) ? bsum[t] : 0;
    s[t] = v;
    __syncthreads();
#pragma unroll
    for (int off = 1; off < 256; off <<= 1) {
        int u = (t >= off) ? s[t - off] : 0;
        __syncthreads();
        s[t] += u;
        __syncthreads();
    }
    if (t < nb) boff[t] = s[t] - v;      // exclusive offset
    if (t == 255) *rowptr_last = s[255]; // total edge count -> rowptr[N]
}

// per-chunk inclusive scan + block offset -> rowptr, cursor; also inv_deg
__global__ __launch_bounds__(256) void write_rowptr_k(const int* __restrict__ deg,
                                                      const int* __restrict__ boff,
                                                      int* __restrict__ rowptr,
                                                      int* __restrict__ cursor,
                                                      float* __restrict__ inv, int n) {
    __shared__ int s[256];
    int t = threadIdx.x, b = blockIdx.x;
    int i = b * 256 + t;
    int d = (i < n) ? deg[i] : 0;
    s[t] = d;
    __syncthreads();
#pragma unroll
    for (int off = 1; off < 256; off <<= 1) {
        int u = (t >= off) ? s[t - off] : 0;
        __syncthreads();
        s[t] += u;
        __syncthreads();
    }
    if (i < n) {
        int r = boff[b] + s[t] - d;   // exclusive position for node i
        rowptr[i] = r;
        cursor[i] = r;
        inv[i] = 1.0f / fmaxf((float)d, 1.0f);
    }
}

__global__ void scatter_k(const int* __restrict__ src, const int* __restrict__ dst,
                          int* __restrict__ cursor, int* __restrict__ csr, int nE) {
    int i = blockIdx.x * blockDim.x + threadIdx.x;
    if (i < nE) {
        int pos = atomicAdd(cursor + dst[i], 1);
        csr[pos] = src[i];
    }
}

// ---------------- fp32 GEMM: out[N,DOUT] = A[N,128] @ W[128,DOUT] (+bias) ----------------
// tile: 64 rows x 64 cols per block, 256 threads, 4x4 acc per thread.

template <int DOUT>
__global__ __launch_bounds__(256) void gemm_k(const float* __restrict__ A,
                                              const float* __restrict__ W,
                                              const float* __restrict__ bias,
                                              float* __restrict__ out, int N) {
    __shared__ float As[128][65];   // [k][m], stride 65 words
    __shared__ float Ws[128][64];   // [k][n]
    const int bm = blockIdx.x * 64;
    const int bn = blockIdx.y * 64;
    const int tid = threadIdx.x;

    {
        const int kq = tid & 31, rl = tid >> 5;
#pragma unroll
        for (int i = 0; i < 8; ++i) {
            int r = rl + i * 8;
            int row = bm + r;
            float4 v = make_float4(0.f, 0.f, 0.f, 0.f);
            if (row < N) v = *(const float4*)(A + (size_t)row * 128 + kq * 4);
            As[kq * 4 + 0][r] = v.x;
            As[kq * 4 + 1][r] = v.y;
            As[kq * 4 + 2][r] = v.z;
            As[kq * 4 + 3][r] = v.w;
        }
        const int cq = tid & 15, kl = tid >> 4;
#pragma unroll
        for (int i = 0; i < 8; ++i) {
            int k = kl + i * 16;
            *(float4*)(&Ws[k][cq * 4]) = *(const float4*)(W + (size_t)k * DOUT + bn + cq * 4);
        }
    }
    __syncthreads();

    const int tc = tid & 15, tr = tid >> 4;
    float acc[4][4] = {};
#pragma unroll 8
    for (int k = 0; k < 128; ++k) {
        float a0 = As[k][tr * 4 + 0];
        float a1 = As[k][tr * 4 + 1];
        float a2 = As[k][tr * 4 + 2];
        float a3 = As[k][tr * 4 + 3];
        float4 b = *(const float4*)(&Ws[k][tc * 4]);
        acc[0][0] += a0 * b.x; acc[0][1] += a0 * b.y; acc[0][2] += a0 * b.z; acc[0][3] += a0 * b.w;
        acc[1][0] += a1 * b.x; acc[1][1] += a1 * b.y; acc[1][2] += a1 * b.z; acc[1][3] += a1 * b.w;
        acc[2][0] += a2 * b.x; acc[2][1] += a2 * b.y; acc[2][2] += a2 * b.z; acc[2][3] += a2 * b.w;
        acc[3][0] += a3 * b.x; acc[3][1] += a3 * b.y; acc[3][2] += a3 * b.z; acc[3][3] += a3 * b.w;
    }

    float4 bb = make_float4(0.f, 0.f, 0.f, 0.f);
    if (bias) bb = *(const float4*)(bias + bn + tc * 4);
#pragma unroll
    for (int i = 0; i < 4; ++i) {
        int row = bm + tr * 4 + i;
        if (row < N) {
            float4 o;
            o.x = acc[i][0] + bb.x;
            o.y = acc[i][1] + bb.y;
            o.z = acc[i][2] + bb.z;
            o.w = acc[i][3] + bb.w;
            *(float4*)(out + (size_t)row * DOUT + bn + tc * 4) = o;
        }
    }
}

// ---------------- aggregation: out[v] += inv[v] * sum_j z[csr[j]]  (+optional relu) ----------------
// one wave per node; lane-parallel over feature columns.

template <int DOUT, bool RELU>
__global__ __launch_bounds__(256) void agg_k(const float* __restrict__ z,
                                             const int* __restrict__ rowptr,
                                             const int* __restrict__ csr,
                                             const float* __restrict__ inv,
                                             float* __restrict__ out, int N) {
    int gwave = (blockIdx.x * 256 + threadIdx.x) >> 6;
    int lane = threadIdx.x & 63;
    if (gwave >= N) return;
    const int v = gwave;
    int start = rowptr[v], end = rowptr[v + 1];

    if constexpr (DOUT == 128) {
        const float2* zp = (const float2*)z;
        float2 a0 = {0.f, 0.f}, a1 = {0.f, 0.f};
        int j = start;
        for (; j + 1 < end; j += 2) {
            int u0 = csr[j], u1 = csr[j + 1];
            float2 v0 = zp[(size_t)u0 * 64 + lane];
            float2 v1 = zp[(size_t)u1 * 64 + lane];
            a0.x += v0.x; a0.y += v0.y;
            a1.x += v1.x; a1.y += v1.y;
        }
        if (j < end) {
            int u = csr[j];
            float2 vv = zp[(size_t)u * 64 + lane];
            a0.x += vv.x; a0.y += vv.y;
        }
        float s = inv[v];
        float2* op = (float2*)(out + (size_t)v * 128) + lane;
        float2 o = *op;
        o.x += (a0.x + a1.x) * s;
        o.y += (a0.y + a1.y) * s;
        if (RELU) { o.x = fmaxf(o.x, 0.f); o.y = fmaxf(o.y, 0.f); }
        *op = o;
    } else {
        float a0 = 0.f, a1 = 0.f;
        int j = start;
        for (; j + 1 < end; j += 2) {
            int u0 = csr[j], u1 = csr[j + 1];
            a0 += z[(size_t)u0 * DOUT + lane];
            a1 += z[(size_t)u1 * DOUT + lane];
        }
        if (j < end) a0 += z[(size_t)csr[j] * DOUT + lane];
        float s = inv[v];
        float* op = out + (size_t)v * DOUT + lane;
        float o = *op + (a0 + a1) * s;
        if (RELU) o = fmaxf(o, 0.f);
        *op = o;
    }
}

// ---------------- launch ----------------

extern "C" void kernel_launch(void* const* d_in, const int* in_sizes, int n_in,
                              void* d_out, int out_size, void* d_ws, size_t ws_size,
                              hipStream_t stream) {
    const float* x       = (const float*)d_in[0];
    const int*   src     = (const int*)d_in[1];
    const int*   dst     = (const int*)d_in[2];
    const float* Wself0  = (const float*)d_in[3];
    const float* Wneigh0 = (const float*)d_in[4];
    const float* b0      = (const float*)d_in[5];
    const float* Wself1  = (const float*)d_in[6];
    const float* Wneigh1 = (const float*)d_in[7];
    const float* b1      = (const float*)d_in[8];
    const float* Wself2  = (const float*)d_in[9];
    const float* Wneigh2 = (const float*)d_in[10];
    const float* b2      = (const float*)d_in[11];
    float* out = (float*)d_out;

    char* ws = (char*)d_ws;
    size_t off = 0;
    auto alloc = [&](size_t bytes) -> void* {
        void* p = ws + off;
        off += (bytes + 255) & ~(size_t)255;
        return p;
    };
    int*   deg    = (int*)alloc((size_t)N_NODES * 4);
    float* inv    = (float*)alloc((size_t)N_NODES * 4);
    int*   rowptr = (int*)alloc((size_t)(N_NODES + 1) * 4);
    int*   cursor = (int*)alloc((size_t)N_NODES * 4);
    int*   csr    = (int*)alloc((size_t)N_EDGES * 4);
    int*   bsum   = (int*)alloc((size_t)NB_SCAN * 4);
    int*   boff   = (int*)alloc((size_t)NB_SCAN * 4);
    float* bufA   = (float*)alloc((size_t)N_NODES * 128 * 4);
    float* bufB   = (float*)alloc((size_t)N_NODES * 128 * 4);
    float* bufZ   = (float*)alloc((size_t)N_NODES * 128 * 4);

    dim3 b256(256);
    const int edgeBlocks = (N_EDGES + 255) / 256;
    const int gemmRows   = (N_NODES + 63) / 64;   // 782
    const int aggBlocks  = (N_NODES + 3) / 4;     // 4 waves (nodes) per 256-thread block

    // ---- CSR build (hierarchical scan, all coalesced) ----
    hipMemsetAsync(deg, 0, (size_t)N_NODES * 4, stream);
    deg_count_k<<<edgeBlocks, b256, 0, stream>>>(dst, deg, N_EDGES);
    block_sum_k<<<NB_SCAN, b256, 0, stream>>>(deg, bsum, N_NODES);
    scan_bsum_k<<<1, b256, 0, stream>>>(bsum, boff, rowptr + N_NODES, NB_SCAN);
    write_rowptr_k<<<NB_SCAN, b256, 0, stream>>>(deg, boff, rowptr, cursor, inv, N_NODES);
    scatter_k<<<edgeBlocks, b256, 0, stream>>>(src, dst, cursor, csr, N_EDGES);

    // layer 0: x[50000,128] -> bufA
    gemm_k<128><<<dim3(gemmRows, 2), b256, 0, stream>>>(x, Wneigh0, nullptr, bufZ, N_NODES);
    gemm_k<128><<<dim3(gemmRows, 2), b256, 0, stream>>>(x, Wself0, b0, bufA, N_NODES);
    agg_k<128, true><<<aggBlocks, b256, 0, stream>>>(bufZ, rowptr, csr, inv, bufA, N_NODES);

    // layer 1: bufA -> bufB
    gemm_k<128><<<dim3(gemmRows, 2), b256, 0, stream>>>(bufA, Wneigh1, nullptr, bufZ, N_NODES);
    gemm_k<128><<<dim3(gemmRows, 2), b256, 0, stream>>>(bufA, Wself1, b1, bufB, N_NODES);
    agg_k<128, true><<<aggBlocks, b256, 0, stream>>>(bufZ, rowptr, csr, inv, bufB, N_NODES);

    // layer 2: bufB -> out[50000,64]
    gemm_k<64><<<dim3(gemmRows, 1), b256, 0, stream>>>(bufB, Wneigh2, nullptr, bufZ, N_NODES);
    gemm_k<64><<<dim3(gemmRows, 1), b256, 0, stream>>>(bufB, Wself2, b2, out, N_NODES);
    agg_k<64, false><<<aggBlocks, b256, 0, stream>>>(bufZ, rowptr, csr, inv, out, N_NODES);
}

// Round 3
// 395.807 us; speedup vs baseline: 1.5464x; 1.2196x over previous
//
#include <hip/hip_runtime.h>

#define N_NODES 50000
#define N_EDGES 800000
#define NB_SCAN 196   // ceil(50000 / 256)

typedef unsigned short ushort_t;

__device__ __forceinline__ ushort_t f2bf(float f) {
    unsigned u = __float_as_uint(f);
    unsigned r = 0x7fffu + ((u >> 16) & 1u);   // round-to-nearest-even
    return (ushort_t)((u + r) >> 16);
}
__device__ __forceinline__ float bf2f(ushort_t h) {
    return __uint_as_float((unsigned)h << 16);
}

// ---------------- CSR build ----------------

__global__ void deg_count_k(const int* __restrict__ dst, int* __restrict__ deg, int nE) {
    int i = blockIdx.x * blockDim.x + threadIdx.x;
    if (i < nE) atomicAdd(deg + dst[i], 1);
}

__global__ __launch_bounds__(256) void block_sum_k(const int* __restrict__ deg,
                                                   int* __restrict__ bsum, int n) {
    __shared__ int s[256];
    int t = threadIdx.x, b = blockIdx.x;
    int i = b * 256 + t;
    s[t] = (i < n) ? deg[i] : 0;
    __syncthreads();
#pragma unroll
    for (int off = 128; off > 0; off >>= 1) {
        if (t < off) s[t] += s[t + off];
        __syncthreads();
    }
    if (t == 0) bsum[b] = s[0];
}

__global__ __launch_bounds__(256) void scan_bsum_k(const int* __restrict__ bsum,
                                                   int* __restrict__ boff,
                                                   int* __restrict__ rowptr_last, int nb) {
    __shared__ int s[256];
    int t = threadIdx.x;
    int v = (t < nb) ? bsum[t] : 0;
    s[t] = v;
    __syncthreads();
#pragma unroll
    for (int off = 1; off < 256; off <<= 1) {
        int u = (t >= off) ? s[t - off] : 0;
        __syncthreads();
        s[t] += u;
        __syncthreads();
    }
    if (t < nb) boff[t] = s[t] - v;
    if (t == 255) *rowptr_last = s[255];
}

__global__ __launch_bounds__(256) void write_rowptr_k(const int* __restrict__ deg,
                                                      const int* __restrict__ boff,
                                                      int* __restrict__ rowptr,
                                                      int* __restrict__ cursor,
                                                      float* __restrict__ inv, int n) {
    __shared__ int s[256];
    int t = threadIdx.x, b = blockIdx.x;
    int i = b * 256 + t;
    int d = (i < n) ? deg[i] : 0;
    s[t] = d;
    __syncthreads();
#pragma unroll
    for (int off = 1; off < 256; off <<= 1) {
        int u = (t >= off) ? s[t - off] : 0;
        __syncthreads();
        s[t] += u;
        __syncthreads();
    }
    if (i < n) {
        int r = boff[b] + s[t] - d;
        rowptr[i] = r;
        cursor[i] = r;
        inv[i] = 1.0f / fmaxf((float)d, 1.0f);
    }
}

__global__ void scatter_k(const int* __restrict__ src, const int* __restrict__ dst,
                          int* __restrict__ cursor, int* __restrict__ csr, int nE) {
    int i = blockIdx.x * blockDim.x + threadIdx.x;
    if (i < nE) {
        int pos = atomicAdd(cursor + dst[i], 1);
        csr[pos] = src[i];
    }
}

// ---------------- fp32 GEMM: out[N,DOUT] = A[N,128] @ W[128,DOUT] (+bias) ----------------
// 64x64 tile per block, 256 threads, 4x4 acc. BF16OUT stores bf16 (for z).

template <int DOUT, bool BF16OUT>
__global__ __launch_bounds__(256) void gemm_k(const float* __restrict__ A,
                                              const float* __restrict__ W,
                                              const float* __restrict__ bias,
                                              void* __restrict__ outv, int N) {
    __shared__ float As[128][65];
    __shared__ float Ws[128][64];
    const int bm = blockIdx.x * 64;
    const int bn = blockIdx.y * 64;
    const int tid = threadIdx.x;

    {
        const int kq = tid & 31, rl = tid >> 5;
#pragma unroll
        for (int i = 0; i < 8; ++i) {
            int r = rl + i * 8;
            int row = bm + r;
            float4 v = make_float4(0.f, 0.f, 0.f, 0.f);
            if (row < N) v = *(const float4*)(A + (size_t)row * 128 + kq * 4);
            As[kq * 4 + 0][r] = v.x;
            As[kq * 4 + 1][r] = v.y;
            As[kq * 4 + 2][r] = v.z;
            As[kq * 4 + 3][r] = v.w;
        }
        const int cq = tid & 15, kl = tid >> 4;
#pragma unroll
        for (int i = 0; i < 8; ++i) {
            int k = kl + i * 16;
            *(float4*)(&Ws[k][cq * 4]) = *(const float4*)(W + (size_t)k * DOUT + bn + cq * 4);
        }
    }
    __syncthreads();

    const int tc = tid & 15, tr = tid >> 4;
    float acc[4][4] = {};
#pragma unroll 8
    for (int k = 0; k < 128; ++k) {
        float a0 = As[k][tr * 4 + 0];
        float a1 = As[k][tr * 4 + 1];
        float a2 = As[k][tr * 4 + 2];
        float a3 = As[k][tr * 4 + 3];
        float4 b = *(const float4*)(&Ws[k][tc * 4]);
        acc[0][0] += a0 * b.x; acc[0][1] += a0 * b.y; acc[0][2] += a0 * b.z; acc[0][3] += a0 * b.w;
        acc[1][0] += a1 * b.x; acc[1][1] += a1 * b.y; acc[1][2] += a1 * b.z; acc[1][3] += a1 * b.w;
        acc[2][0] += a2 * b.x; acc[2][1] += a2 * b.y; acc[2][2] += a2 * b.z; acc[2][3] += a2 * b.w;
        acc[3][0] += a3 * b.x; acc[3][1] += a3 * b.y; acc[3][2] += a3 * b.z; acc[3][3] += a3 * b.w;
    }

    float4 bb = make_float4(0.f, 0.f, 0.f, 0.f);
    if (bias) bb = *(const float4*)(bias + bn + tc * 4);
#pragma unroll
    for (int i = 0; i < 4; ++i) {
        int row = bm + tr * 4 + i;
        if (row < N) {
            float ox = acc[i][0] + bb.x;
            float oy = acc[i][1] + bb.y;
            float oz = acc[i][2] + bb.z;
            float ow = acc[i][3] + bb.w;
            if constexpr (BF16OUT) {
                ushort4 h;
                h.x = f2bf(ox); h.y = f2bf(oy); h.z = f2bf(oz); h.w = f2bf(ow);
                *(ushort4*)((ushort_t*)outv + (size_t)row * DOUT + bn + tc * 4) = h;
            } else {
                float4 o = make_float4(ox, oy, oz, ow);
                *(float4*)((float*)outv + (size_t)row * DOUT + bn + tc * 4) = o;
            }
        }
    }
}

// ---------------- aggregation over bf16 z: out[v] = relu?(out[v] + inv[v]*sum_j z[csr[j]]) ----------------

// DOUT=128: one wave per node; lane reads ushort2 (2 bf16) per row; 4-deep edge unroll.
template <bool RELU>
__global__ __launch_bounds__(256) void agg128_k(const ushort_t* __restrict__ z,
                                                const int* __restrict__ rowptr,
                                                const int* __restrict__ csr,
                                                const float* __restrict__ inv,
                                                float* __restrict__ out, int N) {
    int gwave = (blockIdx.x * 256 + threadIdx.x) >> 6;
    int lane = threadIdx.x & 63;
    if (gwave >= N) return;
    const int v = gwave;
    int start = rowptr[v], end = rowptr[v + 1];

    const ushort2* zp = (const ushort2*)z;   // row stride 64 ushort2
    float ax0 = 0.f, ay0 = 0.f, ax1 = 0.f, ay1 = 0.f;
    float ax2 = 0.f, ay2 = 0.f, ax3 = 0.f, ay3 = 0.f;
    int j = start;
    for (; j + 3 < end; j += 4) {
        int u0 = csr[j], u1 = csr[j + 1], u2 = csr[j + 2], u3 = csr[j + 3];
        ushort2 w0 = zp[(size_t)u0 * 64 + lane];
        ushort2 w1 = zp[(size_t)u1 * 64 + lane];
        ushort2 w2 = zp[(size_t)u2 * 64 + lane];
        ushort2 w3 = zp[(size_t)u3 * 64 + lane];
        ax0 += bf2f(w0.x); ay0 += bf2f(w0.y);
        ax1 += bf2f(w1.x); ay1 += bf2f(w1.y);
        ax2 += bf2f(w2.x); ay2 += bf2f(w2.y);
        ax3 += bf2f(w3.x); ay3 += bf2f(w3.y);
    }
    for (; j < end; ++j) {
        int u = csr[j];
        ushort2 w = zp[(size_t)u * 64 + lane];
        ax0 += bf2f(w.x); ay0 += bf2f(w.y);
    }
    float s = inv[v];
    float2* op = (float2*)(out + (size_t)v * 128) + lane;
    float2 o = *op;
    o.x += ((ax0 + ax1) + (ax2 + ax3)) * s;
    o.y += ((ay0 + ay1) + (ay2 + ay3)) * s;
    if (RELU) { o.x = fmaxf(o.x, 0.f); o.y = fmaxf(o.y, 0.f); }
    *op = o;
}

// DOUT=64: one wave per node, two 32-lane halves each gather a different edge.
__global__ __launch_bounds__(256) void agg64_k(const ushort_t* __restrict__ z,
                                               const int* __restrict__ rowptr,
                                               const int* __restrict__ csr,
                                               const float* __restrict__ inv,
                                               float* __restrict__ out, int N) {
    int gwave = (blockIdx.x * 256 + threadIdx.x) >> 6;
    int lane = threadIdx.x & 63;
    if (gwave >= N) return;
    const int v = gwave;
    const int h = lane >> 5;      // which edge within a pair
    const int c = lane & 31;      // column pair index (2 bf16 per lane)
    int start = rowptr[v], end = rowptr[v + 1];

    const ushort2* zp = (const ushort2*)z;   // row stride 32 ushort2
    float ax0 = 0.f, ay0 = 0.f, ax1 = 0.f, ay1 = 0.f;
    int j = start;
    for (; j + 3 < end; j += 4) {
        int u0 = csr[j + h], u1 = csr[j + 2 + h];
        ushort2 w0 = zp[(size_t)u0 * 32 + c];
        ushort2 w1 = zp[(size_t)u1 * 32 + c];
        ax0 += bf2f(w0.x); ay0 += bf2f(w0.y);
        ax1 += bf2f(w1.x); ay1 += bf2f(w1.y);
    }
    for (; j + 1 < end; j += 2) {
        int u = csr[j + h];
        ushort2 w = zp[(size_t)u * 32 + c];
        ax0 += bf2f(w.x); ay0 += bf2f(w.y);
    }
    if (j < end && h == 0) {
        int u = csr[j];
        ushort2 w = zp[(size_t)u * 32 + c];
        ax0 += bf2f(w.x); ay0 += bf2f(w.y);
    }
    float ax = ax0 + ax1, ay = ay0 + ay1;
    ax += __shfl_xor(ax, 32);
    ay += __shfl_xor(ay, 32);
    if (h == 0) {
        float s = inv[v];
        float2* op = (float2*)(out + (size_t)v * 64) + c;
        float2 o = *op;
        o.x += ax * s;
        o.y += ay * s;
        *op = o;
    }
}

// ---------------- launch ----------------

extern "C" void kernel_launch(void* const* d_in, const int* in_sizes, int n_in,
                              void* d_out, int out_size, void* d_ws, size_t ws_size,
                              hipStream_t stream) {
    const float* x       = (const float*)d_in[0];
    const int*   src     = (const int*)d_in[1];
    const int*   dst     = (const int*)d_in[2];
    const float* Wself0  = (const float*)d_in[3];
    const float* Wneigh0 = (const float*)d_in[4];
    const float* b0      = (const float*)d_in[5];
    const float* Wself1  = (const float*)d_in[6];
    const float* Wneigh1 = (const float*)d_in[7];
    const float* b1      = (const float*)d_in[8];
    const float* Wself2  = (const float*)d_in[9];
    const float* Wneigh2 = (const float*)d_in[10];
    const float* b2      = (const float*)d_in[11];
    float* out = (float*)d_out;

    char* ws = (char*)d_ws;
    size_t off = 0;
    auto alloc = [&](size_t bytes) -> void* {
        void* p = ws + off;
        off += (bytes + 255) & ~(size_t)255;
        return p;
    };
    int*      deg    = (int*)alloc((size_t)N_NODES * 4);
    float*    inv    = (float*)alloc((size_t)N_NODES * 4);
    int*      rowptr = (int*)alloc((size_t)(N_NODES + 1) * 4);
    int*      cursor = (int*)alloc((size_t)N_NODES * 4);
    int*      csr    = (int*)alloc((size_t)N_EDGES * 4);
    int*      bsum   = (int*)alloc((size_t)NB_SCAN * 4);
    int*      boff   = (int*)alloc((size_t)NB_SCAN * 4);
    float*    bufA   = (float*)alloc((size_t)N_NODES * 128 * 4);
    float*    bufB   = (float*)alloc((size_t)N_NODES * 128 * 4);
    ushort_t* bufZ   = (ushort_t*)alloc((size_t)N_NODES * 128 * 2);

    dim3 b256(256);
    const int edgeBlocks = (N_EDGES + 255) / 256;
    const int gemmRows   = (N_NODES + 63) / 64;   // 782
    const int aggBlocks  = (N_NODES + 3) / 4;

    // ---- CSR build ----
    hipMemsetAsync(deg, 0, (size_t)N_NODES * 4, stream);
    deg_count_k<<<edgeBlocks, b256, 0, stream>>>(dst, deg, N_EDGES);
    block_sum_k<<<NB_SCAN, b256, 0, stream>>>(deg, bsum, N_NODES);
    scan_bsum_k<<<1, b256, 0, stream>>>(bsum, boff, rowptr + N_NODES, NB_SCAN);
    write_rowptr_k<<<NB_SCAN, b256, 0, stream>>>(deg, boff, rowptr, cursor, inv, N_NODES);
    scatter_k<<<edgeBlocks, b256, 0, stream>>>(src, dst, cursor, csr, N_EDGES);

    // layer 0: x[50000,128] -> bufA
    gemm_k<128, true ><<<dim3(gemmRows, 2), b256, 0, stream>>>(x, Wneigh0, nullptr, bufZ, N_NODES);
    gemm_k<128, false><<<dim3(gemmRows, 2), b256, 0, stream>>>(x, Wself0, b0, bufA, N_NODES);
    agg128_k<true><<<aggBlocks, b256, 0, stream>>>(bufZ, rowptr, csr, inv, bufA, N_NODES);

    // layer 1: bufA -> bufB
    gemm_k<128, true ><<<dim3(gemmRows, 2), b256, 0, stream>>>(bufA, Wneigh1, nullptr, bufZ, N_NODES);
    gemm_k<128, false><<<dim3(gemmRows, 2), b256, 0, stream>>>(bufA, Wself1, b1, bufB, N_NODES);
    agg128_k<true><<<aggBlocks, b256, 0, stream>>>(bufZ, rowptr, csr, inv, bufB, N_NODES);

    // layer 2: bufB -> out[50000,64]
    gemm_k<64, true ><<<dim3(gemmRows, 1), b256, 0, stream>>>(bufB, Wneigh2, nullptr, bufZ, N_NODES);
    gemm_k<64, false><<<dim3(gemmRows, 1), b256, 0, stream>>>(bufB, Wself2, b2, out, N_NODES);
    agg64_k<<<aggBlocks, b256, 0, stream>>>(bufZ, rowptr, csr, inv, out, N_NODES);
}

// Round 4
// 251.772 us; speedup vs baseline: 2.4311x; 1.5721x over previous
//
#include <hip/hip_runtime.h>

#define N_NODES 50000
#define N_EDGES 800000
#define NB_SCAN 196   // ceil(50000 / 256)

typedef unsigned short ushort_t;
typedef __attribute__((ext_vector_type(8))) short  short8v;   // 8 bf16 (4 VGPR) MFMA A/B frag
typedef __attribute__((ext_vector_type(4))) float  float4v;   // MFMA C/D frag
typedef __attribute__((ext_vector_type(4))) unsigned short ushort4v;
typedef __attribute__((ext_vector_type(8))) unsigned short ushort8v;

__device__ __forceinline__ ushort_t f2bf(float f) {
    unsigned u = __float_as_uint(f);
    unsigned r = 0x7fffu + ((u >> 16) & 1u);   // round-to-nearest-even
    return (ushort_t)((u + r) >> 16);
}
__device__ __forceinline__ float bf2f(ushort_t h) {
    return __uint_as_float((unsigned)h << 16);
}

// ---------------- CSR build ----------------

__global__ void deg_count_k(const int* __restrict__ dst, int* __restrict__ deg, int nE) {
    int i = blockIdx.x * blockDim.x + threadIdx.x;
    if (i < nE) atomicAdd(deg + dst[i], 1);
}

__global__ __launch_bounds__(256) void block_sum_k(const int* __restrict__ deg,
                                                   int* __restrict__ bsum, int n) {
    __shared__ int s[256];
    int t = threadIdx.x, b = blockIdx.x;
    int i = b * 256 + t;
    s[t] = (i < n) ? deg[i] : 0;
    __syncthreads();
#pragma unroll
    for (int off = 128; off > 0; off >>= 1) {
        if (t < off) s[t] += s[t + off];
        __syncthreads();
    }
    if (t == 0) bsum[b] = s[0];
}

__global__ __launch_bounds__(256) void scan_bsum_k(const int* __restrict__ bsum,
                                                   int* __restrict__ boff,
                                                   int* __restrict__ rowptr_last, int nb) {
    __shared__ int s[256];
    int t = threadIdx.x;
    int v = (t < nb) ? bsum[t] : 0;
    s[t] = v;
    __syncthreads();
#pragma unroll
    for (int off = 1; off < 256; off <<= 1) {
        int u = (t >= off) ? s[t - off] : 0;
        __syncthreads();
        s[t] += u;
        __syncthreads();
    }
    if (t < nb) boff[t] = s[t] - v;
    if (t == 255) *rowptr_last = s[255];
}

__global__ __launch_bounds__(256) void write_rowptr_k(const int* __restrict__ deg,
                                                      const int* __restrict__ boff,
                                                      int* __restrict__ rowptr,
                                                      int* __restrict__ cursor,
                                                      float* __restrict__ inv, int n) {
    __shared__ int s[256];
    int t = threadIdx.x, b = blockIdx.x;
    int i = b * 256 + t;
    int d = (i < n) ? deg[i] : 0;
    s[t] = d;
    __syncthreads();
#pragma unroll
    for (int off = 1; off < 256; off <<= 1) {
        int u = (t >= off) ? s[t - off] : 0;
        __syncthreads();
        s[t] += u;
        __syncthreads();
    }
    if (i < n) {
        int r = boff[b] + s[t] - d;
        rowptr[i] = r;
        cursor[i] = r;
        inv[i] = 1.0f / fmaxf((float)d, 1.0f);
    }
}

// XCD-range-partitioned scatter: group g = blockIdx%8 handles dst in [g*6250,(g+1)*6250).
// Each group re-scans all edges; csr writes stay within one XCD's 400KB region -> full lines.
__global__ __launch_bounds__(256) void scatter_k(const int* __restrict__ src,
                                                 const int* __restrict__ dst,
                                                 int* __restrict__ cursor,
                                                 int* __restrict__ csr, int nE) {
    const int grp = blockIdx.x & 7;
    const int lo = grp * 6250, hi = lo + 6250;
    const int stride = (gridDim.x >> 3) * 256;
    for (int i = (blockIdx.x >> 3) * 256 + threadIdx.x; i < nE; i += stride) {
        int d = dst[i];
        if (d >= lo && d < hi) {
            int s = src[i];
            int pos = atomicAdd(cursor + d, 1);
            csr[pos] = s;
        }
    }
}

// ---------------- weight packing: fp32 W[128][DOUT] -> bf16 fragment layout ----------------
// frag index r = (nt*4 + ks)*64 + lane ; elem j: W[ks*32 + (lane>>4)*8 + j][nt*16 + (lane&15)]

__global__ __launch_bounds__(256) void pack_all_k(const float* __restrict__ W0n, const float* __restrict__ W0s,
                                                  const float* __restrict__ W1n, const float* __restrict__ W1s,
                                                  const float* __restrict__ W2n, const float* __restrict__ W2s,
                                                  ushort_t* __restrict__ P) {
    int tid = blockIdx.x * 256 + threadIdx.x;
    const float* W; int dout; int base; int r;
    if      (tid < 2048)  { W = W0n; dout = 128; base = 0;     r = tid; }
    else if (tid < 4096)  { W = W0s; dout = 128; base = 16384; r = tid - 2048; }
    else if (tid < 6144)  { W = W1n; dout = 128; base = 32768; r = tid - 4096; }
    else if (tid < 8192)  { W = W1s; dout = 128; base = 49152; r = tid - 6144; }
    else if (tid < 9216)  { W = W2n; dout = 64;  base = 65536; r = tid - 8192; }
    else                  { W = W2s; dout = 64;  base = 73728; r = tid - 9216; }
    int lane = r & 63;
    int ks = (r >> 6) & 3;
    int nt = r >> 8;
    int col = nt * 16 + (lane & 15);
    int k0 = ks * 32 + ((lane >> 4) << 3);
    ushort_t* d = P + (size_t)base + (size_t)r * 8;
    ushort4v lo4, hi4;
#pragma unroll
    for (int j = 0; j < 4; ++j) lo4[j] = f2bf(W[(size_t)(k0 + j) * dout + col]);
#pragma unroll
    for (int j = 0; j < 4; ++j) hi4[j] = f2bf(W[(size_t)(k0 + 4 + j) * dout + col]);
    *(ushort4v*)d = lo4;
    *(ushort4v*)(d + 4) = hi4;
}

// ---------------- fused dual GEMM (bf16 MFMA): S = A@Wself + b (fp32), Z = bf16(A@Wneigh) ----------------
// block: 128 rows, 4 waves (32 rows each), full K=128 staged once in LDS (XOR-swizzled).

template <typename IN_T, int DOUT>
__global__ __launch_bounds__(256, 2) void dualgemm_k(const IN_T* __restrict__ A,
                                                     const short8v* __restrict__ Wn,
                                                     const short8v* __restrict__ Ws,
                                                     const float* __restrict__ bias,
                                                     ushort_t* __restrict__ Z,
                                                     float* __restrict__ S, int N) {
    constexpr int NT = DOUT / 16;
    __shared__ ushort_t Asm[128 * 128];   // 32 KB bf16, [row][k], byte ^= (row&7)<<4
    char* sb = (char*)Asm;
    const int bm = blockIdx.x * 128;
    const int t = threadIdx.x;
    const int w = t >> 6, l = t & 63;

    if constexpr (sizeof(IN_T) == 4) {   // fp32 input (layer 0)
        const float4* Ap = (const float4*)A;
#pragma unroll
        for (int it = 0; it < 16; ++it) {
            int r = it * 8 + (t >> 5);
            int row = bm + r;
            float4 v = make_float4(0.f, 0.f, 0.f, 0.f);
            if (row < N) v = Ap[(size_t)row * 32 + (t & 31)];
            ushort4v h;
            h[0] = f2bf(v.x); h[1] = f2bf(v.y); h[2] = f2bf(v.z); h[3] = f2bf(v.w);
            int byte = (r * 256 + (t & 31) * 8) ^ ((r & 7) << 4);
            *(ushort4v*)(sb + byte) = h;
        }
    } else {                              // bf16 input (layers 1,2)
        const ushort8v* Ap = (const ushort8v*)A;
#pragma unroll
        for (int it = 0; it < 8; ++it) {
            int r = it * 16 + (t >> 4);
            int row = bm + r;
            ushort8v v = {0, 0, 0, 0, 0, 0, 0, 0};
            if (row < N) v = Ap[(size_t)row * 16 + (t & 15)];
            int byte = (r * 256 + (t & 15) * 16) ^ ((r & 7) << 4);
            *(ushort8v*)(sb + byte) = v;
        }
    }
    __syncthreads();

    float bv[NT];
#pragma unroll
    for (int nt = 0; nt < NT; ++nt) bv[nt] = bias[nt * 16 + (l & 15)];

    float4v accS[2][NT] = {}, accN[2][NT] = {};
#pragma unroll
    for (int ks = 0; ks < 4; ++ks) {
        int r0 = w * 32 + (l & 15);
        int b0 = (r0 * 256 + ks * 64 + (l >> 4) * 16) ^ ((r0 & 7) << 4);
        short8v a0 = *(const short8v*)(sb + b0);
        int r1 = r0 + 16;
        int b1 = (r1 * 256 + ks * 64 + (l >> 4) * 16) ^ ((r1 & 7) << 4);
        short8v a1 = *(const short8v*)(sb + b1);
#pragma unroll
        for (int nt = 0; nt < NT; ++nt) {
            short8v bs = Ws[(nt * 4 + ks) * 64 + l];
            short8v bn = Wn[(nt * 4 + ks) * 64 + l];
            accS[0][nt] = __builtin_amdgcn_mfma_f32_16x16x32_bf16(a0, bs, accS[0][nt], 0, 0, 0);
            accS[1][nt] = __builtin_amdgcn_mfma_f32_16x16x32_bf16(a1, bs, accS[1][nt], 0, 0, 0);
            accN[0][nt] = __builtin_amdgcn_mfma_f32_16x16x32_bf16(a0, bn, accN[0][nt], 0, 0, 0);
            accN[1][nt] = __builtin_amdgcn_mfma_f32_16x16x32_bf16(a1, bn, accN[1][nt], 0, 0, 0);
        }
    }

    // epilogue: C/D layout col=lane&15, row=(lane>>4)*4+i  [verified m89]
#pragma unroll
    for (int mi = 0; mi < 2; ++mi) {
#pragma unroll
        for (int i = 0; i < 4; ++i) {
            int row = bm + w * 32 + mi * 16 + (l >> 4) * 4 + i;
            if (row < N) {
#pragma unroll
                for (int nt = 0; nt < NT; ++nt) {
                    int col = nt * 16 + (l & 15);
                    S[(size_t)row * DOUT + col] = accS[mi][nt][i] + bv[nt];
                    Z[(size_t)row * DOUT + col] = f2bf(accN[mi][nt][i]);
                }
            }
        }
    }
}

// ---------------- aggregation ----------------

// DOUT=128: h = relu(S + inv*sum z[nbr]) -> bf16 out. One wave per node, 4-deep unroll.
__global__ __launch_bounds__(256) void agg128_k(const ushort_t* __restrict__ z,
                                                const int* __restrict__ rowptr,
                                                const int* __restrict__ csr,
                                                const float* __restrict__ inv,
                                                const float* __restrict__ Sin,
                                                ushort_t* __restrict__ Hout, int N) {
    int gwave = (blockIdx.x * 256 + threadIdx.x) >> 6;
    int lane = threadIdx.x & 63;
    if (gwave >= N) return;
    const int v = gwave;
    int start = rowptr[v], end = rowptr[v + 1];

    const ushort2* zp = (const ushort2*)z;   // row stride 64 ushort2
    float ax0 = 0.f, ay0 = 0.f, ax1 = 0.f, ay1 = 0.f;
    float ax2 = 0.f, ay2 = 0.f, ax3 = 0.f, ay3 = 0.f;
    int j = start;
    for (; j + 3 < end; j += 4) {
        int u0 = csr[j], u1 = csr[j + 1], u2 = csr[j + 2], u3 = csr[j + 3];
        ushort2 w0 = zp[(size_t)u0 * 64 + lane];
        ushort2 w1 = zp[(size_t)u1 * 64 + lane];
        ushort2 w2 = zp[(size_t)u2 * 64 + lane];
        ushort2 w3 = zp[(size_t)u3 * 64 + lane];
        ax0 += bf2f(w0.x); ay0 += bf2f(w0.y);
        ax1 += bf2f(w1.x); ay1 += bf2f(w1.y);
        ax2 += bf2f(w2.x); ay2 += bf2f(w2.y);
        ax3 += bf2f(w3.x); ay3 += bf2f(w3.y);
    }
    for (; j < end; ++j) {
        int u = csr[j];
        ushort2 w = zp[(size_t)u * 64 + lane];
        ax0 += bf2f(w.x); ay0 += bf2f(w.y);
    }
    float s = inv[v];
    float2 si = ((const float2*)Sin)[(size_t)v * 64 + lane];
    float ox = si.x + ((ax0 + ax1) + (ax2 + ax3)) * s;
    float oy = si.y + ((ay0 + ay1) + (ay2 + ay3)) * s;
    ox = fmaxf(ox, 0.f);
    oy = fmaxf(oy, 0.f);
    ushort2 h;
    h.x = f2bf(ox); h.y = f2bf(oy);
    ((ushort2*)Hout)[(size_t)v * 64 + lane] = h;
}

// DOUT=64: out(fp32, already = S) += inv*sum z[nbr]. Two 32-lane halves gather different edges.
__global__ __launch_bounds__(256) void agg64_k(const ushort_t* __restrict__ z,
                                               const int* __restrict__ rowptr,
                                               const int* __restrict__ csr,
                                               const float* __restrict__ inv,
                                               float* __restrict__ out, int N) {
    int gwave = (blockIdx.x * 256 + threadIdx.x) >> 6;
    int lane = threadIdx.x & 63;
    if (gwave >= N) return;
    const int v = gwave;
    const int h = lane >> 5;
    const int c = lane & 31;
    int start = rowptr[v], end = rowptr[v + 1];

    const ushort2* zp = (const ushort2*)z;   // row stride 32 ushort2
    float ax0 = 0.f, ay0 = 0.f, ax1 = 0.f, ay1 = 0.f;
    int j = start;
    for (; j + 3 < end; j += 4) {
        int u0 = csr[j + h], u1 = csr[j + 2 + h];
        ushort2 w0 = zp[(size_t)u0 * 32 + c];
        ushort2 w1 = zp[(size_t)u1 * 32 + c];
        ax0 += bf2f(w0.x); ay0 += bf2f(w0.y);
        ax1 += bf2f(w1.x); ay1 += bf2f(w1.y);
    }
    for (; j + 1 < end; j += 2) {
        int u = csr[j + h];
        ushort2 w = zp[(size_t)u * 32 + c];
        ax0 += bf2f(w.x); ay0 += bf2f(w.y);
    }
    if (j < end && h == 0) {
        int u = csr[j];
        ushort2 w = zp[(size_t)u * 32 + c];
        ax0 += bf2f(w.x); ay0 += bf2f(w.y);
    }
    float ax = ax0 + ax1, ay = ay0 + ay1;
    ax += __shfl_xor(ax, 32);
    ay += __shfl_xor(ay, 32);
    if (h == 0) {
        float s = inv[v];
        float2* op = (float2*)(out + (size_t)v * 64) + c;
        float2 o = *op;
        o.x += ax * s;
        o.y += ay * s;
        *op = o;
    }
}

// ---------------- launch ----------------

extern "C" void kernel_launch(void* const* d_in, const int* in_sizes, int n_in,
                              void* d_out, int out_size, void* d_ws, size_t ws_size,
                              hipStream_t stream) {
    const float* x       = (const float*)d_in[0];
    const int*   src     = (const int*)d_in[1];
    const int*   dst     = (const int*)d_in[2];
    const float* Wself0  = (const float*)d_in[3];
    const float* Wneigh0 = (const float*)d_in[4];
    const float* b0      = (const float*)d_in[5];
    const float* Wself1  = (const float*)d_in[6];
    const float* Wneigh1 = (const float*)d_in[7];
    const float* b1      = (const float*)d_in[8];
    const float* Wself2  = (const float*)d_in[9];
    const float* Wneigh2 = (const float*)d_in[10];
    const float* b2      = (const float*)d_in[11];
    float* out = (float*)d_out;

    char* ws = (char*)d_ws;
    size_t off = 0;
    auto alloc = [&](size_t bytes) -> void* {
        void* p = ws + off;
        off += (bytes + 255) & ~(size_t)255;
        return p;
    };
    int*      deg    = (int*)alloc((size_t)N_NODES * 4);
    float*    inv    = (float*)alloc((size_t)N_NODES * 4);
    int*      rowptr = (int*)alloc((size_t)(N_NODES + 1) * 4);
    int*      cursor = (int*)alloc((size_t)N_NODES * 4);
    int*      csr    = (int*)alloc((size_t)N_EDGES * 4);
    int*      bsum   = (int*)alloc((size_t)NB_SCAN * 4);
    int*      boff   = (int*)alloc((size_t)NB_SCAN * 4);
    ushort_t* packW  = (ushort_t*)alloc((size_t)81920 * 2);
    float*    sbuf   = (float*)alloc((size_t)N_NODES * 128 * 4);
    ushort_t* hA     = (ushort_t*)alloc((size_t)N_NODES * 128 * 2);
    ushort_t* hB     = (ushort_t*)alloc((size_t)N_NODES * 128 * 2);
    ushort_t* zbuf   = (ushort_t*)alloc((size_t)N_NODES * 128 * 2);

    dim3 b256(256);
    const int edgeBlocks = (N_EDGES + 255) / 256;
    const int gemmBlocks = (N_NODES + 127) / 128;   // 391
    const int aggBlocks  = (N_NODES + 3) / 4;

    // ---- CSR build ----
    hipMemsetAsync(deg, 0, (size_t)N_NODES * 4, stream);
    deg_count_k<<<edgeBlocks, b256, 0, stream>>>(dst, deg, N_EDGES);
    block_sum_k<<<NB_SCAN, b256, 0, stream>>>(deg, bsum, N_NODES);
    scan_bsum_k<<<1, b256, 0, stream>>>(bsum, boff, rowptr + N_NODES, NB_SCAN);
    write_rowptr_k<<<NB_SCAN, b256, 0, stream>>>(deg, boff, rowptr, cursor, inv, N_NODES);
    scatter_k<<<1024, b256, 0, stream>>>(src, dst, cursor, csr, N_EDGES);

    // ---- weight packing (bf16 fragment layout) ----
    pack_all_k<<<40, b256, 0, stream>>>(Wneigh0, Wself0, Wneigh1, Wself1, Wneigh2, Wself2, packW);
    const short8v* pN0 = (const short8v*)(packW);
    const short8v* pS0 = (const short8v*)(packW + 16384);
    const short8v* pN1 = (const short8v*)(packW + 32768);
    const short8v* pS1 = (const short8v*)(packW + 49152);
    const short8v* pN2 = (const short8v*)(packW + 65536);
    const short8v* pS2 = (const short8v*)(packW + 73728);

    // layer 0: x fp32 -> S(sbuf fp32), Z(bf16); agg -> hA bf16
    dualgemm_k<float, 128><<<gemmBlocks, b256, 0, stream>>>(x, pN0, pS0, b0, zbuf, sbuf, N_NODES);
    agg128_k<<<aggBlocks, b256, 0, stream>>>(zbuf, rowptr, csr, inv, sbuf, hA, N_NODES);

    // layer 1: hA bf16 -> S, Z; agg -> hB bf16
    dualgemm_k<ushort_t, 128><<<gemmBlocks, b256, 0, stream>>>(hA, pN1, pS1, b1, zbuf, sbuf, N_NODES);
    agg128_k<<<aggBlocks, b256, 0, stream>>>(zbuf, rowptr, csr, inv, sbuf, hB, N_NODES);

    // layer 2: hB bf16 -> S(d_out fp32), Z; agg adds into d_out
    dualgemm_k<ushort_t, 64><<<gemmBlocks, b256, 0, stream>>>(hB, pN2, pS2, b2, zbuf, out, N_NODES);
    agg64_k<<<aggBlocks, b256, 0, stream>>>(zbuf, rowptr, csr, inv, out, N_NODES);
}

// Round 5
// 225.293 us; speedup vs baseline: 2.7169x; 1.1175x over previous
//
#include <hip/hip_runtime.h>

#define N_NODES 50000
#define N_EDGES 800000
#define NB_SCAN 196   // ceil(50000 / 256)

typedef unsigned short ushort_t;
typedef __attribute__((ext_vector_type(8))) short  short8v;   // 8 bf16 (4 VGPR) MFMA A/B frag
typedef __attribute__((ext_vector_type(4))) float  float4v;   // MFMA C/D frag
typedef __attribute__((ext_vector_type(4))) unsigned short ushort4v;
typedef __attribute__((ext_vector_type(8))) unsigned short ushort8v;

__device__ __forceinline__ ushort_t f2bf(float f) {
    unsigned u = __float_as_uint(f);
    unsigned r = 0x7fffu + ((u >> 16) & 1u);   // round-to-nearest-even
    return (ushort_t)((u + r) >> 16);
}
__device__ __forceinline__ float bf2f(ushort_t h) {
    return __uint_as_float((unsigned)h << 16);
}

// ---------------- CSR build ----------------

__global__ void deg_count_k(const int* __restrict__ dst, int* __restrict__ deg, int nE) {
    int i = blockIdx.x * blockDim.x + threadIdx.x;
    if (i < nE) atomicAdd(deg + dst[i], 1);
}

__global__ __launch_bounds__(256) void block_sum_k(const int* __restrict__ deg,
                                                   int* __restrict__ bsum, int n) {
    __shared__ int s[256];
    int t = threadIdx.x, b = blockIdx.x;
    int i = b * 256 + t;
    s[t] = (i < n) ? deg[i] : 0;
    __syncthreads();
#pragma unroll
    for (int off = 128; off > 0; off >>= 1) {
        if (t < off) s[t] += s[t + off];
        __syncthreads();
    }
    if (t == 0) bsum[b] = s[0];
}

__global__ __launch_bounds__(256) void scan_bsum_k(const int* __restrict__ bsum,
                                                   int* __restrict__ boff,
                                                   int* __restrict__ rowptr_last, int nb) {
    __shared__ int s[256];
    int t = threadIdx.x;
    int v = (t < nb) ? bsum[t] : 0;
    s[t] = v;
    __syncthreads();
#pragma unroll
    for (int off = 1; off < 256; off <<= 1) {
        int u = (t >= off) ? s[t - off] : 0;
        __syncthreads();
        s[t] += u;
        __syncthreads();
    }
    if (t < nb) boff[t] = s[t] - v;
    if (t == 255) *rowptr_last = s[255];
}

__global__ __launch_bounds__(256) void write_rowptr_k(const int* __restrict__ deg,
                                                      const int* __restrict__ boff,
                                                      int* __restrict__ rowptr,
                                                      int* __restrict__ cursor,
                                                      float* __restrict__ inv, int n) {
    __shared__ int s[256];
    int t = threadIdx.x, b = blockIdx.x;
    int i = b * 256 + t;
    int d = (i < n) ? deg[i] : 0;
    s[t] = d;
    __syncthreads();
#pragma unroll
    for (int off = 1; off < 256; off <<= 1) {
        int u = (t >= off) ? s[t - off] : 0;
        __syncthreads();
        s[t] += u;
        __syncthreads();
    }
    if (i < n) {
        int r = boff[b] + s[t] - d;
        rowptr[i] = r;
        cursor[i] = r;
        inv[i] = 1.0f / fmaxf((float)d, 1.0f);
    }
}

// XCD-range-partitioned scatter (keeps csr writes local to one XCD's L2)
__global__ __launch_bounds__(256) void scatter_k(const int* __restrict__ src,
                                                 const int* __restrict__ dst,
                                                 int* __restrict__ cursor,
                                                 int* __restrict__ csr, int nE) {
    const int grp = blockIdx.x & 7;
    const int lo = grp * 6250, hi = lo + 6250;
    const int stride = (gridDim.x >> 3) * 256;
    for (int i = (blockIdx.x >> 3) * 256 + threadIdx.x; i < nE; i += stride) {
        int d = dst[i];
        if (d >= lo && d < hi) {
            int s = src[i];
            int pos = atomicAdd(cursor + d, 1);
            csr[pos] = s;
        }
    }
}

// ---------------- x fp32 -> bf16 cast ----------------
__global__ __launch_bounds__(256) void cast_bf16_k(const float* __restrict__ x,
                                                   ushort_t* __restrict__ xb, int n4) {
    int i = blockIdx.x * 256 + threadIdx.x;
    if (i < n4) {
        float4 v = ((const float4*)x)[i];
        ushort4v h;
        h[0] = f2bf(v.x); h[1] = f2bf(v.y); h[2] = f2bf(v.z); h[3] = f2bf(v.w);
        ((ushort4v*)xb)[i] = h;
    }
}

// ---------------- weight packing: fp32 W[128][DOUT] -> bf16 MFMA B-fragment layout ----------------
__global__ __launch_bounds__(256) void pack_all_k(const float* __restrict__ W0n, const float* __restrict__ W0s,
                                                  const float* __restrict__ W1n, const float* __restrict__ W1s,
                                                  const float* __restrict__ W2n, const float* __restrict__ W2s,
                                                  ushort_t* __restrict__ P) {
    int tid = blockIdx.x * 256 + threadIdx.x;
    const float* W; int dout; int base; int r;
    if      (tid < 2048)  { W = W0n; dout = 128; base = 0;     r = tid; }
    else if (tid < 4096)  { W = W0s; dout = 128; base = 16384; r = tid - 2048; }
    else if (tid < 6144)  { W = W1n; dout = 128; base = 32768; r = tid - 4096; }
    else if (tid < 8192)  { W = W1s; dout = 128; base = 49152; r = tid - 6144; }
    else if (tid < 9216)  { W = W2n; dout = 64;  base = 65536; r = tid - 8192; }
    else                  { W = W2s; dout = 64;  base = 73728; r = tid - 9216; }
    int lane = r & 63;
    int ks = (r >> 6) & 3;
    int nt = r >> 8;
    int col = nt * 16 + (lane & 15);
    int k0 = ks * 32 + ((lane >> 4) << 3);
    ushort_t* d = P + (size_t)base + (size_t)r * 8;
    ushort4v lo4, hi4;
#pragma unroll
    for (int j = 0; j < 4; ++j) lo4[j] = f2bf(W[(size_t)(k0 + j) * dout + col]);
#pragma unroll
    for (int j = 0; j < 4; ++j) hi4[j] = f2bf(W[(size_t)(k0 + 4 + j) * dout + col]);
    *(ushort4v*)d = lo4;
    *(ushort4v*)(d + 4) = hi4;
}

// ---------------- gather-mean: m[v] = bf16( inv[v] * sum_j h[csr[j]] )  (128-wide bf16) ----------------
// 32 lanes per node (ushort4 = 8B per lane per row), 2 nodes per wave, 4-edge unroll.
__global__ __launch_bounds__(256) void aggm_k(const ushort_t* __restrict__ h,
                                              const int* __restrict__ rowptr,
                                              const int* __restrict__ csr,
                                              const float* __restrict__ inv,
                                              ushort_t* __restrict__ m, int N) {
    int node = (blockIdx.x * 256 + threadIdx.x) >> 5;
    int c = threadIdx.x & 31;
    if (node >= N) return;
    int start = rowptr[node], end = rowptr[node + 1];

    const ushort4v* hp = (const ushort4v*)h;   // row stride 32 (256 B)
    float a0[4] = {}, a1[4] = {}, a2[4] = {}, a3[4] = {};
    int j = start;
    for (; j + 3 < end; j += 4) {
        int u0 = csr[j], u1 = csr[j + 1], u2 = csr[j + 2], u3 = csr[j + 3];
        ushort4v w0 = hp[(size_t)u0 * 32 + c];
        ushort4v w1 = hp[(size_t)u1 * 32 + c];
        ushort4v w2 = hp[(size_t)u2 * 32 + c];
        ushort4v w3 = hp[(size_t)u3 * 32 + c];
#pragma unroll
        for (int k = 0; k < 4; ++k) {
            a0[k] += bf2f(w0[k]); a1[k] += bf2f(w1[k]);
            a2[k] += bf2f(w2[k]); a3[k] += bf2f(w3[k]);
        }
    }
    for (; j < end; ++j) {
        ushort4v w = hp[(size_t)csr[j] * 32 + c];
#pragma unroll
        for (int k = 0; k < 4; ++k) a0[k] += bf2f(w[k]);
    }
    float s = inv[node];
    ushort4v o;
#pragma unroll
    for (int k = 0; k < 4; ++k) o[k] = f2bf(((a0[k] + a1[k]) + (a2[k] + a3[k])) * s);
    ((ushort4v*)m)[(size_t)node * 32 + c] = o;
}

// ---------------- fused dual-A GEMM: Out = bf16(relu(H@Ws + M@Wn + b))  [128 -> 128] ----------------
// block: 128 rows, 4 waves; H-tile and M-tile both staged in LDS (XOR-swizzled), shared accumulator.
__global__ __launch_bounds__(256, 2) void fusedgemm_k(const ushort_t* __restrict__ H,
                                                      const ushort_t* __restrict__ M,
                                                      const short8v* __restrict__ Ws,
                                                      const short8v* __restrict__ Wn,
                                                      const float* __restrict__ bias,
                                                      ushort_t* __restrict__ Out, int N) {
    __shared__ ushort_t sm[2][128 * 128];   // 2 x 32 KB
    char* sbH = (char*)sm[0];
    char* sbM = (char*)sm[1];
    const int bm = blockIdx.x * 128;
    const int t = threadIdx.x;
    const int w = t >> 6, l = t & 63;

    {
        const ushort8v* Hp = (const ushort8v*)H;
        const ushort8v* Mp = (const ushort8v*)M;
        ushort8v zeroV = {0, 0, 0, 0, 0, 0, 0, 0};
#pragma unroll
        for (int it = 0; it < 8; ++it) {
            int r = it * 16 + (t >> 4);
            int row = bm + r;
            int byte = (r * 256 + (t & 15) * 16) ^ ((r & 7) << 4);
            ushort8v vh = zeroV, vm = zeroV;
            if (row < N) {
                vh = Hp[(size_t)row * 16 + (t & 15)];
                vm = Mp[(size_t)row * 16 + (t & 15)];
            }
            *(ushort8v*)(sbH + byte) = vh;
            *(ushort8v*)(sbM + byte) = vm;
        }
    }
    __syncthreads();

    float bv[8];
#pragma unroll
    for (int nt = 0; nt < 8; ++nt) bv[nt] = bias[nt * 16 + (l & 15)];

    float4v acc[2][8] = {};
#pragma unroll
    for (int ks = 0; ks < 4; ++ks) {
        int r0 = w * 32 + (l & 15);
        int r1 = r0 + 16;
        int b0 = (r0 * 256 + ks * 64 + (l >> 4) * 16) ^ ((r0 & 7) << 4);
        int b1 = (r1 * 256 + ks * 64 + (l >> 4) * 16) ^ ((r1 & 7) << 4);
        short8v ah0 = *(const short8v*)(sbH + b0);
        short8v ah1 = *(const short8v*)(sbH + b1);
        short8v am0 = *(const short8v*)(sbM + b0);
        short8v am1 = *(const short8v*)(sbM + b1);
#pragma unroll
        for (int nt = 0; nt < 8; ++nt) {
            short8v bs = Ws[(nt * 4 + ks) * 64 + l];
            short8v bn = Wn[(nt * 4 + ks) * 64 + l];
            acc[0][nt] = __builtin_amdgcn_mfma_f32_16x16x32_bf16(ah0, bs, acc[0][nt], 0, 0, 0);
            acc[0][nt] = __builtin_amdgcn_mfma_f32_16x16x32_bf16(am0, bn, acc[0][nt], 0, 0, 0);
            acc[1][nt] = __builtin_amdgcn_mfma_f32_16x16x32_bf16(ah1, bs, acc[1][nt], 0, 0, 0);
            acc[1][nt] = __builtin_amdgcn_mfma_f32_16x16x32_bf16(am1, bn, acc[1][nt], 0, 0, 0);
        }
    }

    // C/D layout: col = lane&15, row = (lane>>4)*4 + i  [verified m89]
#pragma unroll
    for (int mi = 0; mi < 2; ++mi) {
#pragma unroll
        for (int i = 0; i < 4; ++i) {
            int row = bm + w * 32 + mi * 16 + (l >> 4) * 4 + i;
            if (row < N) {
#pragma unroll
                for (int nt = 0; nt < 8; ++nt) {
                    int col = nt * 16 + (l & 15);
                    Out[(size_t)row * 128 + col] = f2bf(fmaxf(acc[mi][nt][i] + bv[nt], 0.f));
                }
            }
        }
    }
}

// ---------------- layer-2 dual GEMM: S(fp32, ->out) = H@Wself + b ; Z(bf16) = H@Wneigh  [128 -> 64] ----------------
__global__ __launch_bounds__(256, 2) void dual64_k(const ushort_t* __restrict__ A,
                                                   const short8v* __restrict__ Wn,
                                                   const short8v* __restrict__ Ws,
                                                   const float* __restrict__ bias,
                                                   ushort_t* __restrict__ Z,
                                                   float* __restrict__ S, int N) {
    constexpr int NT = 4;
    __shared__ ushort_t Asm[128 * 128];
    char* sb = (char*)Asm;
    const int bm = blockIdx.x * 128;
    const int t = threadIdx.x;
    const int w = t >> 6, l = t & 63;

    {
        const ushort8v* Ap = (const ushort8v*)A;
        ushort8v zeroV = {0, 0, 0, 0, 0, 0, 0, 0};
#pragma unroll
        for (int it = 0; it < 8; ++it) {
            int r = it * 16 + (t >> 4);
            int row = bm + r;
            ushort8v v = zeroV;
            if (row < N) v = Ap[(size_t)row * 16 + (t & 15)];
            int byte = (r * 256 + (t & 15) * 16) ^ ((r & 7) << 4);
            *(ushort8v*)(sb + byte) = v;
        }
    }
    __syncthreads();

    float bv[NT];
#pragma unroll
    for (int nt = 0; nt < NT; ++nt) bv[nt] = bias[nt * 16 + (l & 15)];

    float4v accS[2][NT] = {}, accN[2][NT] = {};
#pragma unroll
    for (int ks = 0; ks < 4; ++ks) {
        int r0 = w * 32 + (l & 15);
        int b0 = (r0 * 256 + ks * 64 + (l >> 4) * 16) ^ ((r0 & 7) << 4);
        short8v a0 = *(const short8v*)(sb + b0);
        int r1 = r0 + 16;
        int b1 = (r1 * 256 + ks * 64 + (l >> 4) * 16) ^ ((r1 & 7) << 4);
        short8v a1 = *(const short8v*)(sb + b1);
#pragma unroll
        for (int nt = 0; nt < NT; ++nt) {
            short8v bs = Ws[(nt * 4 + ks) * 64 + l];
            short8v bn = Wn[(nt * 4 + ks) * 64 + l];
            accS[0][nt] = __builtin_amdgcn_mfma_f32_16x16x32_bf16(a0, bs, accS[0][nt], 0, 0, 0);
            accS[1][nt] = __builtin_amdgcn_mfma_f32_16x16x32_bf16(a1, bs, accS[1][nt], 0, 0, 0);
            accN[0][nt] = __builtin_amdgcn_mfma_f32_16x16x32_bf16(a0, bn, accN[0][nt], 0, 0, 0);
            accN[1][nt] = __builtin_amdgcn_mfma_f32_16x16x32_bf16(a1, bn, accN[1][nt], 0, 0, 0);
        }
    }

#pragma unroll
    for (int mi = 0; mi < 2; ++mi) {
#pragma unroll
        for (int i = 0; i < 4; ++i) {
            int row = bm + w * 32 + mi * 16 + (l >> 4) * 4 + i;
            if (row < N) {
#pragma unroll
                for (int nt = 0; nt < NT; ++nt) {
                    int col = nt * 16 + (l & 15);
                    S[(size_t)row * 64 + col] = accS[mi][nt][i] + bv[nt];
                    Z[(size_t)row * 64 + col] = f2bf(accN[mi][nt][i]);
                }
            }
        }
    }
}

// ---------------- layer-2 aggregation: out(fp32,=S) += inv * sum z[nbr]  (64-wide) ----------------
// 16 lanes per node (ushort4 = 8B per lane), 4 nodes per wave, 4-edge unroll.
__global__ __launch_bounds__(256) void agg64_k(const ushort_t* __restrict__ z,
                                               const int* __restrict__ rowptr,
                                               const int* __restrict__ csr,
                                               const float* __restrict__ inv,
                                               float* __restrict__ out, int N) {
    int node = (blockIdx.x * 256 + threadIdx.x) >> 4;
    int c = threadIdx.x & 15;
    if (node >= N) return;
    int start = rowptr[node], end = rowptr[node + 1];

    const ushort4v* zp = (const ushort4v*)z;   // row stride 16 (128 B)
    float a0[4] = {}, a1[4] = {}, a2[4] = {}, a3[4] = {};
    int j = start;
    for (; j + 3 < end; j += 4) {
        int u0 = csr[j], u1 = csr[j + 1], u2 = csr[j + 2], u3 = csr[j + 3];
        ushort4v w0 = zp[(size_t)u0 * 16 + c];
        ushort4v w1 = zp[(size_t)u1 * 16 + c];
        ushort4v w2 = zp[(size_t)u2 * 16 + c];
        ushort4v w3 = zp[(size_t)u3 * 16 + c];
#pragma unroll
        for (int k = 0; k < 4; ++k) {
            a0[k] += bf2f(w0[k]); a1[k] += bf2f(w1[k]);
            a2[k] += bf2f(w2[k]); a3[k] += bf2f(w3[k]);
        }
    }
    for (; j < end; ++j) {
        ushort4v w = zp[(size_t)csr[j] * 16 + c];
#pragma unroll
        for (int k = 0; k < 4; ++k) a0[k] += bf2f(w[k]);
    }
    float s = inv[node];
    float4* op = (float4*)(out + (size_t)node * 64 + c * 4);
    float4 o = *op;
    o.x += ((a0[0] + a1[0]) + (a2[0] + a3[0])) * s;
    o.y += ((a0[1] + a1[1]) + (a2[1] + a3[1])) * s;
    o.z += ((a0[2] + a1[2]) + (a2[2] + a3[2])) * s;
    o.w += ((a0[3] + a1[3]) + (a2[3] + a3[3])) * s;
    *op = o;
}

// ---------------- launch ----------------

extern "C" void kernel_launch(void* const* d_in, const int* in_sizes, int n_in,
                              void* d_out, int out_size, void* d_ws, size_t ws_size,
                              hipStream_t stream) {
    const float* x       = (const float*)d_in[0];
    const int*   src     = (const int*)d_in[1];
    const int*   dst     = (const int*)d_in[2];
    const float* Wself0  = (const float*)d_in[3];
    const float* Wneigh0 = (const float*)d_in[4];
    const float* b0      = (const float*)d_in[5];
    const float* Wself1  = (const float*)d_in[6];
    const float* Wneigh1 = (const float*)d_in[7];
    const float* b1      = (const float*)d_in[8];
    const float* Wself2  = (const float*)d_in[9];
    const float* Wneigh2 = (const float*)d_in[10];
    const float* b2      = (const float*)d_in[11];
    float* out = (float*)d_out;

    char* ws = (char*)d_ws;
    size_t off = 0;
    auto alloc = [&](size_t bytes) -> void* {
        void* p = ws + off;
        off += (bytes + 255) & ~(size_t)255;
        return p;
    };
    int*      deg    = (int*)alloc((size_t)N_NODES * 4);
    float*    inv    = (float*)alloc((size_t)N_NODES * 4);
    int*      rowptr = (int*)alloc((size_t)(N_NODES + 1) * 4);
    int*      cursor = (int*)alloc((size_t)N_NODES * 4);
    int*      csr    = (int*)alloc((size_t)N_EDGES * 4);
    int*      bsum   = (int*)alloc((size_t)NB_SCAN * 4);
    int*      boff   = (int*)alloc((size_t)NB_SCAN * 4);
    ushort_t* packW  = (ushort_t*)alloc((size_t)81920 * 2);
    ushort_t* xb     = (ushort_t*)alloc((size_t)N_NODES * 128 * 2);
    ushort_t* mbuf   = (ushort_t*)alloc((size_t)N_NODES * 128 * 2);
    ushort_t* h1     = (ushort_t*)alloc((size_t)N_NODES * 128 * 2);
    ushort_t* h2     = (ushort_t*)alloc((size_t)N_NODES * 128 * 2);
    ushort_t* z64    = (ushort_t*)alloc((size_t)N_NODES * 64 * 2);

    dim3 b256(256);
    const int edgeBlocks  = (N_EDGES + 255) / 256;
    const int gemmBlocks  = (N_NODES + 127) / 128;        // 391
    const int aggmBlocks  = (N_NODES * 32 + 255) / 256;   // 6250
    const int agg64Blocks = (N_NODES * 16 + 255) / 256;   // 3125
    const int castBlocks  = (N_NODES * 128 / 4 + 255) / 256;

    // ---- CSR build ----
    hipMemsetAsync(deg, 0, (size_t)N_NODES * 4, stream);
    deg_count_k<<<edgeBlocks, b256, 0, stream>>>(dst, deg, N_EDGES);
    block_sum_k<<<NB_SCAN, b256, 0, stream>>>(deg, bsum, N_NODES);
    scan_bsum_k<<<1, b256, 0, stream>>>(bsum, boff, rowptr + N_NODES, NB_SCAN);
    write_rowptr_k<<<NB_SCAN, b256, 0, stream>>>(deg, boff, rowptr, cursor, inv, N_NODES);
    scatter_k<<<1024, b256, 0, stream>>>(src, dst, cursor, csr, N_EDGES);

    // ---- weight packing + input cast ----
    pack_all_k<<<40, b256, 0, stream>>>(Wneigh0, Wself0, Wneigh1, Wself1, Wneigh2, Wself2, packW);
    cast_bf16_k<<<castBlocks, b256, 0, stream>>>(x, xb, N_NODES * 128 / 4);
    const short8v* pN0 = (const short8v*)(packW);
    const short8v* pS0 = (const short8v*)(packW + 16384);
    const short8v* pN1 = (const short8v*)(packW + 32768);
    const short8v* pS1 = (const short8v*)(packW + 49152);
    const short8v* pN2 = (const short8v*)(packW + 65536);
    const short8v* pS2 = (const short8v*)(packW + 73728);

    // layer 0 (agg-first): m = mean(xb[nbr]); h1 = relu(xb@Ws0 + m@Wn0 + b0)
    aggm_k<<<aggmBlocks, b256, 0, stream>>>(xb, rowptr, csr, inv, mbuf, N_NODES);
    fusedgemm_k<<<gemmBlocks, b256, 0, stream>>>(xb, mbuf, pS0, pN0, b0, h1, N_NODES);

    // layer 1 (agg-first): m = mean(h1[nbr]); h2 = relu(h1@Ws1 + m@Wn1 + b1)
    aggm_k<<<aggmBlocks, b256, 0, stream>>>(h1, rowptr, csr, inv, mbuf, N_NODES);
    fusedgemm_k<<<gemmBlocks, b256, 0, stream>>>(h1, mbuf, pS1, pN1, b1, h2, N_NODES);

    // layer 2 (gemm-first): out = h2@Ws2 + b2 ; z = bf16(h2@Wn2) ; out += inv*segsum(z)
    dual64_k<<<gemmBlocks, b256, 0, stream>>>(h2, pN2, pS2, b2, z64, out, N_NODES);
    agg64_k<<<agg64Blocks, b256, 0, stream>>>(z64, rowptr, csr, inv, out, N_NODES);
}